// Round 5
// baseline (88.663 us; speedup 1.0000x reference)
//
#include <hip/hip_runtime.h>
#include <math.h>

// Ultimate Smoother: 2nd-order IIR along T for X of shape (B=32, T=8192, D=256) f32.
// out[0..2] = x[0..2]; out[t] = b1*x[t-1]+b2*x[t-2]+b3*x[t-3]+c2*out[t-1]+c3*out[t-2]
// Chains (b,d) independent; chunk T with warm-up (pole modulus ~0.80, DC gain 1;
// 48-step warm-up -> absmax 0.0156 observed vs threshold 0.21).
//
// R5: LCH 512->1024 (warm-up reads 24.5->11.4 MB; logical traffic 523 MB -> 83 µs
// at the 6.29 TB/s float4-copy ceiling). Grid is now 256 single-wave blocks
// (1 wave/CU), so the pipeline deepens to 4 rotating 8-row buffers = 24
// outstanding loads (24 KB in flight/wave vs ~9 KB Little's-law minimum).

typedef float f4 __attribute__((ext_vector_type(4)));

#define TT 8192
#define BB 32
#define DD 256
#define LCH 1024
#define WARM 48
#define NCH (TT / LCH)   // 8
#define ROW (DD / 4)     // 64 float4s per time row

__device__ __forceinline__ f4 iir4(const f4& xm1, const f4& xm2, const f4& xm3,
                                   const f4& s1, const f4& s2,
                                   float b1, float b2, float b3, float c2, float c3) {
    f4 r;
#pragma unroll
    for (int c = 0; c < 4; ++c) {
        float tmp = fmaf(b3, xm3[c], fmaf(b2, xm2[c], b1 * xm1[c]));  // x-terms: independent
        r[c] = fmaf(c3, s2[c], fmaf(c2, s1[c], tmp));                 // 2 dependent FMAs
    }
    return r;
}

// Load batch bk (8 rows) into BUF if it exists.
#define LOADB(BUF, bk)                                                         \
    do {                                                                       \
        if ((bk) < nb) {                                                       \
            _Pragma("unroll") for (int i = 0; i < 8; ++i)                      \
                BUF[i] = xp[(size_t)(ta + (bk) * 8 + i) * ROW];                \
        }                                                                      \
    } while (0)

// Compute batch k from BUF (already loaded); store rows >= store_from.
#define STEPB(BUF)                                                             \
    do {                                                                       \
        const int bt = ta + k * 8;                                             \
        if (bt >= store_from) {                                                \
            _Pragma("unroll") for (int i = 0; i < 8; ++i) {                    \
                f4 s = iir4(xm1, xm2, xm3, s1, s2, b1, b2, b3, c2, c3);        \
                __builtin_nontemporal_store(s, &op[(size_t)(bt + i) * ROW]);   \
                s2 = s1; s1 = s;                                               \
                xm3 = xm2; xm2 = xm1; xm1 = BUF[i];                            \
            }                                                                  \
        } else {                                                               \
            _Pragma("unroll") for (int i = 0; i < 8; ++i) {                    \
                f4 s = iir4(xm1, xm2, xm3, s1, s2, b1, b2, b3, c2, c3);        \
                s2 = s1; s1 = s;                                               \
                xm3 = xm2; xm2 = xm1; xm1 = BUF[i];                            \
            }                                                                  \
        }                                                                      \
        ++k;                                                                   \
    } while (0)

__device__ __forceinline__ void run_span(const f4* __restrict__ xp, f4* __restrict__ op,
                                         int ta, int tb, int store_from,
                                         f4& xm1, f4& xm2, f4& xm3, f4& s1, f4& s2,
                                         float b1, float b2, float b3, float c2, float c3) {
    // (tb - ta) must be a multiple of 8; warm region (ta..store_from) 8-aligned.
    // 4 rotating buffers, 3-batch lookahead, all indices compile-time (rule #20).
    const int nb = (tb - ta) / 8;
    f4 bA[8], bB[8], bC[8], bD[8];
    LOADB(bA, 0);
    LOADB(bB, 1);
    LOADB(bC, 2);
    int k = 0;
    while (k < nb) {
        LOADB(bD, k + 3);   // issue 3-ahead loads BEFORE waiting on current batch
        STEPB(bA);
        if (k >= nb) break;
        LOADB(bA, k + 3);
        STEPB(bB);
        if (k >= nb) break;
        LOADB(bB, k + 3);
        STEPB(bC);
        if (k >= nb) break;
        LOADB(bC, k + 3);
        STEPB(bD);
    }
}

__global__ __launch_bounds__(64) void ultsmooth_kernel(const f4* __restrict__ X,
                                                       const float* __restrict__ periodp,
                                                       f4* __restrict__ out) {
    const int task  = blockIdx.x;       // 0 .. BB*NCH-1
    const int b     = task / NCH;
    const int chunk = task % NCH;
    const int lane  = threadIdx.x;      // 0..63, each owns 4 d-columns

    // Coefficients (double precision; f32-rounding vs the reference scan plus
    // WARM=48 warm-up gives the observed 1.6e-2 absmax — below the 0.21 threshold).
    const double p   = (double)periodp[0];
    const double a1  = exp(-1.4142135623730951 * M_PI / p);
    const double dc2 = -2.0 * a1 * cos(1.4142135623730951 * 180.0 / p);
    const double dc3 = -a1 * a1;
    const double dc1 = (1.0 + dc2 - dc3) * 0.25;
    const float b1 = (float)(1.0 - dc1);
    const float b2 = (float)(2.0 * dc1 - dc2);
    const float b3 = (float)(-(dc1 + dc3));
    const float c2 = (float)dc2;
    const float c3 = (float)dc3;

    const f4* xp = X   + (size_t)b * TT * ROW + lane;
    f4*       op = out + (size_t)b * TT * ROW + lane;

    f4 xm1, xm2, xm3, s1, s2;
    const int t0 = chunk * LCH;

    if (chunk == 0) {
        // Exact start: out[0..2] = x[0..2]; recurrence from t=3.
        f4 x[8];
#pragma unroll
        for (int i = 0; i < 8; ++i) x[i] = xp[(size_t)i * ROW];
        __builtin_nontemporal_store(x[0], &op[0]);
        __builtin_nontemporal_store(x[1], &op[ROW]);
        __builtin_nontemporal_store(x[2], &op[2 * ROW]);
        xm1 = x[2]; xm2 = x[1]; xm3 = x[0];
        s1 = x[2];  s2 = x[1];
#pragma unroll
        for (int t = 3; t < 8; ++t) {
            f4 s = iir4(xm1, xm2, xm3, s1, s2, b1, b2, b3, c2, c3);
            __builtin_nontemporal_store(s, &op[(size_t)t * ROW]);
            s2 = s1; s1 = s;
            xm3 = xm2; xm2 = xm1; xm1 = x[t];
        }
        run_span(xp, op, 8, LCH, 0, xm1, xm2, xm3, s1, s2, b1, b2, b3, c2, c3);
    } else {
        // Approximate start WARM steps early; state error decays ~(a+bt)*0.80^t.
        const int tw = t0 - WARM;
        xm1 = xp[(size_t)(tw - 1) * ROW];
        xm2 = xp[(size_t)(tw - 2) * ROW];
        xm3 = xp[(size_t)(tw - 3) * ROW];
        s1 = xm1; s2 = xm2;
        run_span(xp, op, tw, t0 + LCH, t0, xm1, xm2, xm3, s1, s2, b1, b2, b3, c2, c3);
    }
}

extern "C" void kernel_launch(void* const* d_in, const int* in_sizes, int n_in,
                              void* d_out, int out_size, void* d_ws, size_t ws_size,
                              hipStream_t stream) {
    const f4*    X      = (const f4*)d_in[0];
    const float* period = (const float*)d_in[1];
    f4*          out    = (f4*)d_out;

    dim3 grid(BB * NCH);   // 32 batches * 8 time-chunks = 256 single-wave blocks
    dim3 block(64);        // one wave; 64 lanes x float4 = all 256 columns
    hipLaunchKernelGGL(ultsmooth_kernel, grid, block, 0, stream, X, period, out);
}

// Round 6
// 86.530 us; speedup vs baseline: 1.0246x; 1.0246x over previous
//
#include <hip/hip_runtime.h>
#include <math.h>

// Ultimate Smoother: 2nd-order IIR along T for X of shape (B=32, T=8192, D=256) f32.
// out[0..2] = x[0..2]; out[t] = b1*x[t-1]+b2*x[t-2]+b3*x[t-3]+c2*out[t-1]+c3*out[t-2]
// Chains (b,d) independent; chunk T with warm-up (pole modulus ~0.80, DC gain 1;
// 48-step warm-up -> absmax 0.0156 observed vs threshold 0.21).
//
// R6: R4 geometry (LCH=512, 512 single-wave blocks = 2 waves/CU — R5 showed
// 1 wave/CU regresses) + R5's deeper pipeline (4 rotating 8-row buffers,
// 3-batch lookahead = 24 outstanding loads/wave) to relax vmcnt wait
// boundaries. Logical traffic 536.5 MB; floor at 6.29 TB/s = 85.3 µs.

typedef float f4 __attribute__((ext_vector_type(4)));

#define TT 8192
#define BB 32
#define DD 256
#define LCH 512
#define WARM 48
#define NCH (TT / LCH)   // 16
#define ROW (DD / 4)     // 64 float4s per time row

__device__ __forceinline__ f4 iir4(const f4& xm1, const f4& xm2, const f4& xm3,
                                   const f4& s1, const f4& s2,
                                   float b1, float b2, float b3, float c2, float c3) {
    f4 r;
#pragma unroll
    for (int c = 0; c < 4; ++c) {
        float tmp = fmaf(b3, xm3[c], fmaf(b2, xm2[c], b1 * xm1[c]));  // x-terms: independent
        r[c] = fmaf(c3, s2[c], fmaf(c2, s1[c], tmp));                 // 2 dependent FMAs
    }
    return r;
}

// Load batch bk (8 rows) into BUF if it exists.
#define LOADB(BUF, bk)                                                         \
    do {                                                                       \
        if ((bk) < nb) {                                                       \
            _Pragma("unroll") for (int i = 0; i < 8; ++i)                      \
                BUF[i] = xp[(size_t)(ta + (bk) * 8 + i) * ROW];                \
        }                                                                      \
    } while (0)

// Compute batch k from BUF (already loaded); store rows >= store_from.
#define STEPB(BUF)                                                             \
    do {                                                                       \
        const int bt = ta + k * 8;                                             \
        if (bt >= store_from) {                                                \
            _Pragma("unroll") for (int i = 0; i < 8; ++i) {                    \
                f4 s = iir4(xm1, xm2, xm3, s1, s2, b1, b2, b3, c2, c3);        \
                __builtin_nontemporal_store(s, &op[(size_t)(bt + i) * ROW]);   \
                s2 = s1; s1 = s;                                               \
                xm3 = xm2; xm2 = xm1; xm1 = BUF[i];                            \
            }                                                                  \
        } else {                                                               \
            _Pragma("unroll") for (int i = 0; i < 8; ++i) {                    \
                f4 s = iir4(xm1, xm2, xm3, s1, s2, b1, b2, b3, c2, c3);        \
                s2 = s1; s1 = s;                                               \
                xm3 = xm2; xm2 = xm1; xm1 = BUF[i];                            \
            }                                                                  \
        }                                                                      \
        ++k;                                                                   \
    } while (0)

__device__ __forceinline__ void run_span(const f4* __restrict__ xp, f4* __restrict__ op,
                                         int ta, int tb, int store_from,
                                         f4& xm1, f4& xm2, f4& xm3, f4& s1, f4& s2,
                                         float b1, float b2, float b3, float c2, float c3) {
    // (tb - ta) must be a multiple of 8; warm region (ta..store_from) 8-aligned.
    // 4 rotating buffers, 3-batch lookahead, all indices compile-time (rule #20).
    const int nb = (tb - ta) / 8;
    f4 bA[8], bB[8], bC[8], bD[8];
    LOADB(bA, 0);
    LOADB(bB, 1);
    LOADB(bC, 2);
    int k = 0;
    while (k < nb) {
        LOADB(bD, k + 3);   // issue 3-ahead loads BEFORE waiting on current batch
        STEPB(bA);
        if (k >= nb) break;
        LOADB(bA, k + 3);
        STEPB(bB);
        if (k >= nb) break;
        LOADB(bB, k + 3);
        STEPB(bC);
        if (k >= nb) break;
        LOADB(bC, k + 3);
        STEPB(bD);
    }
}

__global__ __launch_bounds__(64) void ultsmooth_kernel(const f4* __restrict__ X,
                                                       const float* __restrict__ periodp,
                                                       f4* __restrict__ out) {
    const int task  = blockIdx.x;       // 0 .. BB*NCH-1
    const int b     = task / NCH;
    const int chunk = task % NCH;
    const int lane  = threadIdx.x;      // 0..63, each owns 4 d-columns

    // Coefficients (double precision; f32-rounding vs the reference scan plus
    // WARM=48 warm-up gives the observed 1.6e-2 absmax — below the 0.21 threshold).
    const double p   = (double)periodp[0];
    const double a1  = exp(-1.4142135623730951 * M_PI / p);
    const double dc2 = -2.0 * a1 * cos(1.4142135623730951 * 180.0 / p);
    const double dc3 = -a1 * a1;
    const double dc1 = (1.0 + dc2 - dc3) * 0.25;
    const float b1 = (float)(1.0 - dc1);
    const float b2 = (float)(2.0 * dc1 - dc2);
    const float b3 = (float)(-(dc1 + dc3));
    const float c2 = (float)dc2;
    const float c3 = (float)dc3;

    const f4* xp = X   + (size_t)b * TT * ROW + lane;
    f4*       op = out + (size_t)b * TT * ROW + lane;

    f4 xm1, xm2, xm3, s1, s2;
    const int t0 = chunk * LCH;

    if (chunk == 0) {
        // Exact start: out[0..2] = x[0..2]; recurrence from t=3.
        f4 x[8];
#pragma unroll
        for (int i = 0; i < 8; ++i) x[i] = xp[(size_t)i * ROW];
        __builtin_nontemporal_store(x[0], &op[0]);
        __builtin_nontemporal_store(x[1], &op[ROW]);
        __builtin_nontemporal_store(x[2], &op[2 * ROW]);
        xm1 = x[2]; xm2 = x[1]; xm3 = x[0];
        s1 = x[2];  s2 = x[1];
#pragma unroll
        for (int t = 3; t < 8; ++t) {
            f4 s = iir4(xm1, xm2, xm3, s1, s2, b1, b2, b3, c2, c3);
            __builtin_nontemporal_store(s, &op[(size_t)t * ROW]);
            s2 = s1; s1 = s;
            xm3 = xm2; xm2 = xm1; xm1 = x[t];
        }
        run_span(xp, op, 8, LCH, 0, xm1, xm2, xm3, s1, s2, b1, b2, b3, c2, c3);
    } else {
        // Approximate start WARM steps early; state error decays ~(a+bt)*0.80^t.
        const int tw = t0 - WARM;
        xm1 = xp[(size_t)(tw - 1) * ROW];
        xm2 = xp[(size_t)(tw - 2) * ROW];
        xm3 = xp[(size_t)(tw - 3) * ROW];
        s1 = xm1; s2 = xm2;
        run_span(xp, op, tw, t0 + LCH, t0, xm1, xm2, xm3, s1, s2, b1, b2, b3, c2, c3);
    }
}

extern "C" void kernel_launch(void* const* d_in, const int* in_sizes, int n_in,
                              void* d_out, int out_size, void* d_ws, size_t ws_size,
                              hipStream_t stream) {
    const f4*    X      = (const f4*)d_in[0];
    const float* period = (const float*)d_in[1];
    f4*          out    = (f4*)d_out;

    dim3 grid(BB * NCH);   // 32 batches * 16 time-chunks = 512 single-wave blocks
    dim3 block(64);        // one wave; 64 lanes x float4 = all 256 columns
    hipLaunchKernelGGL(ultsmooth_kernel, grid, block, 0, stream, X, period, out);
}